// Round 1
// baseline (159.909 us; speedup 1.0000x reference)
//
#include <hip/hip_runtime.h>
#include <math.h>

#define B_ROWS 8192
#define F_DIM  64
#define H_DIM  256
#define BLOCK  512
#define ROWS_PER_BLOCK 16
#define RGROUP 4
#define FPT    32   // f values per thread (tables held in registers)

// mish(x) = x * tanh(softplus(x)) = x * (t^2 + 2t) / (t^2 + 2t + 2), t = e^x
// Clamp exp arg at 42: t <= e^42 ~ 1.7e18, t^2 ~ 3e36 (no overflow), and
// ratio rounds to exactly 1.0f, matching mish(x) -> x for large x.
// For very negative x, t underflows to 0 -> ratio 0 -> mish -> 0 (correct).
__device__ __forceinline__ float mish_f(float x) {
    float t   = __expf(fminf(x, 42.0f));          // v_mul + v_exp
    float num = __fmaf_rn(t, t, t + t);           // t^2 + 2t
    float q   = num * __builtin_amdgcn_rcpf(num + 2.0f);
    return x * q;
}

__global__ __launch_bounds__(BLOCK, 4)
void nam_kernel(const float* __restrict__ X,
                const float* __restrict__ exu_w,
                const float* __restrict__ exu_b,
                const float* __restrict__ dense_k,
                const float* __restrict__ dense_b,
                float* __restrict__ out)
{
    __shared__ __align__(16) float xe_lds[RGROUP][F_DIM]; // (X[b,f]-eb[f]) for 4 rows
    __shared__ float red_lds[8][RGROUP];                  // per-wave partials
    __shared__ float sdb;                                 // sum of dense_b

    const int tid   = threadIdx.x;
    const int h     = tid & 255;       // h column this thread owns
    const int half  = tid >> 8;        // 0 or 1
    const int fbase = half * FPT;      // f range [fbase, fbase+32)

    // --- load tables into registers (once per block), fusing exp(exu_w) ---
    float ew_r[FPT], dk_r[FPT];
    #pragma unroll
    for (int j = 0; j < FPT; ++j) {
        const int idx = (fbase + j) * H_DIM + h;   // coalesced across tid
        ew_r[j] = expf(exu_w[idx]);
        dk_r[j] = dense_k[idx];
    }

    // --- sum(dense_b) once per block (wave 0) ---
    if (tid < 64) {
        float v = dense_b[tid];
        #pragma unroll
        for (int off = 32; off > 0; off >>= 1)
            v += __shfl_down(v, off, 64);
        if (tid == 0) sdb = v;
    }

    const int row0 = blockIdx.x * ROWS_PER_BLOCK;

    for (int g = 0; g < ROWS_PER_BLOCK / RGROUP; ++g) {
        const int b0 = row0 + g * RGROUP;

        __syncthreads();  // xe_lds/red_lds safe to overwrite; sdb visible
        if (tid < RGROUP * F_DIM) {
            // flat [r*64 + f] == tid; X[(b0+r)*64 + f] == X[b0*64 + tid]
            float x = X[(size_t)b0 * F_DIM + tid];
            ((float*)xe_lds)[tid] = x - exu_b[tid & 63];
        }
        __syncthreads();

        float acc0 = 0.f, acc1 = 0.f, acc2 = 0.f, acc3 = 0.f;

        #pragma unroll
        for (int j4 = 0; j4 < FPT; j4 += 4) {
            // broadcast LDS reads (all lanes same address -> conflict-free)
            const float4 v0 = *(const float4*)(&xe_lds[0][fbase + j4]);
            const float4 v1 = *(const float4*)(&xe_lds[1][fbase + j4]);
            const float4 v2 = *(const float4*)(&xe_lds[2][fbase + j4]);
            const float4 v3 = *(const float4*)(&xe_lds[3][fbase + j4]);
            const float xr0[4] = {v0.x, v0.y, v0.z, v0.w};
            const float xr1[4] = {v1.x, v1.y, v1.z, v1.w};
            const float xr2[4] = {v2.x, v2.y, v2.z, v2.w};
            const float xr3[4] = {v3.x, v3.y, v3.z, v3.w};
            #pragma unroll
            for (int k = 0; k < 4; ++k) {
                const float ewv = ew_r[j4 + k];
                const float dkv = dk_r[j4 + k];
                // 4 independent chains -> ILP across exp/rcp latency
                acc0 = __fmaf_rn(mish_f(xr0[k] * ewv), dkv, acc0);
                acc1 = __fmaf_rn(mish_f(xr1[k] * ewv), dkv, acc1);
                acc2 = __fmaf_rn(mish_f(xr2[k] * ewv), dkv, acc2);
                acc3 = __fmaf_rn(mish_f(xr3[k] * ewv), dkv, acc3);
            }
        }

        // --- block reduction: wave shuffle, then 8 wave-partials via LDS ---
        #pragma unroll
        for (int off = 32; off > 0; off >>= 1) {
            acc0 += __shfl_down(acc0, off, 64);
            acc1 += __shfl_down(acc1, off, 64);
            acc2 += __shfl_down(acc2, off, 64);
            acc3 += __shfl_down(acc3, off, 64);
        }
        const int wave = tid >> 6;
        const int lane = tid & 63;
        if (lane == 0) {
            red_lds[wave][0] = acc0;
            red_lds[wave][1] = acc1;
            red_lds[wave][2] = acc2;
            red_lds[wave][3] = acc3;
        }
        __syncthreads();
        if (tid < RGROUP) {
            float s = 0.f;
            #pragma unroll
            for (int w = 0; w < 8; ++w) s += red_lds[w][tid];
            out[b0 + tid] = s + sdb;
        }
    }
}

extern "C" void kernel_launch(void* const* d_in, const int* in_sizes, int n_in,
                              void* d_out, int out_size, void* d_ws, size_t ws_size,
                              hipStream_t stream) {
    const float* X  = (const float*)d_in[0];
    const float* ew = (const float*)d_in[1];
    const float* eb = (const float*)d_in[2];
    const float* dk = (const float*)d_in[3];
    const float* db = (const float*)d_in[4];
    float* out = (float*)d_out;

    dim3 grid(B_ROWS / ROWS_PER_BLOCK);   // 512 blocks
    dim3 block(BLOCK);                    // 512 threads
    nam_kernel<<<grid, block, 0, stream>>>(X, ew, eb, dk, db, out);
}

// Round 2
// 112.612 us; speedup vs baseline: 1.4200x; 1.4200x over previous
//
#include <hip/hip_runtime.h>
#include <math.h>

#define B_ROWS 8192
#define F_DIM  64
#define H_DIM  256
#define BLOCK  1024
#define ROWS_PER_BLOCK 16
#define RGROUP 8
#define NPASS  (ROWS_PER_BLOCK / RGROUP)   // 2
#define FPT    16                          // f values per thread (in registers)
#define NWAVES (BLOCK / 64)                // 16

// mish(x) = x * (t^2+2t)/(t^2+2t+2), t = e^x.
// Using q = 1 - 2*rcp(num+2) instead of num*rcp(num+2):
//   t -> inf  => rcp(inf)=0  => q=1  => mish -> x   (no clamp needed, no NaN)
//   t -> 0    => rcp(2)=0.5  => q=0  => mish -> 0
// 9 VALU + 2 trans per element including the x=xe*ew and the acc-fma.
__device__ __forceinline__ float mish_nc(float x) {
    float t   = __expf(x);                        // v_mul(log2e) + v_exp
    float num = __fmaf_rn(t, t, t + t);           // t^2 + 2t
    float r   = __builtin_amdgcn_rcpf(num + 2.0f);
    float q   = __fmaf_rn(-2.0f, r, 1.0f);
    return x * q;
}

__global__ __launch_bounds__(BLOCK, 4)   // cap = 128 VGPR; est ~90 -> no spill
void nam_kernel(const float* __restrict__ X,
                const float* __restrict__ exu_w,
                const float* __restrict__ exu_b,
                const float* __restrict__ dense_k,
                const float* __restrict__ dense_b,
                float* __restrict__ out)
{
    __shared__ __align__(16) float xe_lds[F_DIM][RGROUP]; // (X-eb), transposed: [f][row]
    __shared__ float red_lds[NWAVES][RGROUP];             // per-wave partials
    __shared__ float eb_lds[F_DIM];
    __shared__ float sdb;                                 // sum of dense_b

    const int tid   = threadIdx.x;
    const int h     = tid & (H_DIM - 1);   // h column this thread owns
    const int fq    = tid >> 8;            // 0..3 -> f quarter
    const int fbase = fq * FPT;

    // --- table into registers: only 32 VGPRs/thread ---
    float ew_r[FPT], dk_r[FPT];
    #pragma unroll
    for (int j = 0; j < FPT; ++j) {
        const int idx = (fbase + j) * H_DIM + h;   // coalesced across the wave
        ew_r[j] = __expf(exu_w[idx]);
        dk_r[j] = dense_k[idx];
    }

    if (tid < F_DIM) {
        eb_lds[tid] = exu_b[tid];
        float v = dense_b[tid];
        #pragma unroll
        for (int off = 32; off > 0; off >>= 1) v += __shfl_down(v, off, 64);
        if (tid == 0) sdb = v;
    }

    const int row0 = blockIdx.x * ROWS_PER_BLOCK;

    for (int g = 0; g < NPASS; ++g) {
        const int b0 = row0 + g * RGROUP;

        __syncthreads();   // prev pass fully done; eb_lds/sdb visible (first iter)
        if (tid < RGROUP * F_DIM) {        // 512 threads stage 8 rows
            const int f = tid & (F_DIM - 1);
            const int r = tid >> 6;        // coalesced global read per r-group
            float x = X[(size_t)(b0 + r) * F_DIM + f];
            xe_lds[f][r] = x - eb_lds[f];
        }
        __syncthreads();

        float acc[RGROUP];
        #pragma unroll
        for (int rr = 0; rr < RGROUP; ++rr) acc[rr] = 0.0f;

        const float4* xe4 = (const float4*)xe_lds;  // [F_DIM][2] float4
        #pragma unroll
        for (int j = 0; j < FPT; ++j) {
            const float ewv = ew_r[j];
            const float dkv = dk_r[j];
            // whole wave reads the same address -> LDS broadcast, conflict-free
            const float4 xa = xe4[(fbase + j) * 2 + 0];  // rows 0..3
            const float4 xb = xe4[(fbase + j) * 2 + 1];  // rows 4..7
            acc[0] = __fmaf_rn(mish_nc(xa.x * ewv), dkv, acc[0]);
            acc[1] = __fmaf_rn(mish_nc(xa.y * ewv), dkv, acc[1]);
            acc[2] = __fmaf_rn(mish_nc(xa.z * ewv), dkv, acc[2]);
            acc[3] = __fmaf_rn(mish_nc(xa.w * ewv), dkv, acc[3]);
            acc[4] = __fmaf_rn(mish_nc(xb.x * ewv), dkv, acc[4]);
            acc[5] = __fmaf_rn(mish_nc(xb.y * ewv), dkv, acc[5]);
            acc[6] = __fmaf_rn(mish_nc(xb.z * ewv), dkv, acc[6]);
            acc[7] = __fmaf_rn(mish_nc(xb.w * ewv), dkv, acc[7]);
        }

        // --- wave shuffle reduce, then cross-wave via LDS ---
        #pragma unroll
        for (int rr = 0; rr < RGROUP; ++rr) {
            float v = acc[rr];
            #pragma unroll
            for (int off = 32; off > 0; off >>= 1) v += __shfl_down(v, off, 64);
            acc[rr] = v;
        }
        const int wave = tid >> 6;
        const int lane = tid & 63;
        if (lane == 0) {
            #pragma unroll
            for (int rr = 0; rr < RGROUP; ++rr) red_lds[wave][rr] = acc[rr];
        }
        __syncthreads();
        if (tid < 128) {
            // wave 0 -> rows 0..3, wave 1 -> rows 4..7; lane = w*4 + (r&3)
            const int r = (tid & 3) + (tid >> 6) * 4;
            const int w = (tid & 63) >> 2;
            float v = red_lds[w][r];
            #pragma unroll
            for (int off = 32; off >= 4; off >>= 1) v += __shfl_down(v, off, 64);
            if ((tid & 63) < 4) out[b0 + r] = v + sdb;
        }
    }
}

extern "C" void kernel_launch(void* const* d_in, const int* in_sizes, int n_in,
                              void* d_out, int out_size, void* d_ws, size_t ws_size,
                              hipStream_t stream) {
    const float* X  = (const float*)d_in[0];
    const float* ew = (const float*)d_in[1];
    const float* eb = (const float*)d_in[2];
    const float* dk = (const float*)d_in[3];
    const float* db = (const float*)d_in[4];
    float* out = (float*)d_out;

    dim3 grid(B_ROWS / ROWS_PER_BLOCK);   // 512 blocks -> 2 clean rounds over 256 CUs
    dim3 block(BLOCK);                    // 1024 threads = 16 waves
    nam_kernel<<<grid, block, 0, stream>>>(X, ew, eb, dk, db, out);
}

// Round 3
// 100.150 us; speedup vs baseline: 1.5967x; 1.1244x over previous
//
#include <hip/hip_runtime.h>
#include <math.h>

#define B_ROWS 8192
#define F_DIM  64
#define H_DIM  256
#define BLOCK  1024
#define ROWS_PER_BLOCK 16
#define RGROUP 8
#define NPASS  (ROWS_PER_BLOCK / RGROUP)   // 2
#define FPT    16                          // f values per thread (in registers)
#define NWAVES (BLOCK / 64)                // 16

// mish(x) = x * (t^2+2t)/(t^2+2t+2), t = e^x = 2^(x*log2e).
// With u = t+1:  den = u^2+1 = t^2+2t+2;  q = 1 - 2/den.
//   t -> inf => r=0 => q=1 => contribution = xd   (mish -> x limit, no NaN)
//   t -> 0   => den=2, r=0.5 => q=0               (mish -> 0 limit)
// Tables fold everything possible:
//   ewl = exp(w)*log2e   (so arg = xe*ewl feeds v_exp directly)
//   ewd = exp(w)*dk      (so xd  = xe*ewd is the dk-weighted pre-activation)
// Per element: 6 simple VALU + 2 transcendental.

__global__
__attribute__((amdgpu_flat_work_group_size(BLOCK, BLOCK)))
__attribute__((amdgpu_waves_per_eu(4, 4)))   // pin 128-VGPR budget; stop the
                                             // allocator's 64-reg/8-wave
                                             // heuristic that spilled tables
void nam_kernel(const float* __restrict__ X,
                const float* __restrict__ exu_w,
                const float* __restrict__ exu_b,
                const float* __restrict__ dense_k,
                const float* __restrict__ dense_b,
                float* __restrict__ out)
{
    __shared__ __align__(16) float xe_lds[F_DIM][RGROUP]; // (X-eb), [f][row]
    __shared__ float red_lds[NWAVES][RGROUP];             // per-wave partials
    __shared__ float eb_lds[F_DIM];
    __shared__ float sdb;                                 // sum of dense_b

    const int tid   = threadIdx.x;
    const int h     = tid & (H_DIM - 1);   // h column this thread owns
    const int fq    = tid >> 8;            // 0..3 -> f quarter
    const int fbase = fq * FPT;

    // --- fused tables into registers: 32 VGPRs/thread ---
    float ewl_r[FPT], ewd_r[FPT];
    #pragma unroll
    for (int j = 0; j < FPT; ++j) {
        const int idx = (fbase + j) * H_DIM + h;   // coalesced across the wave
        const float E = __expf(exu_w[idx]);
        ewl_r[j] = E * 1.44269504088896341f;       // exp(w) * log2(e)
        ewd_r[j] = E * dense_k[idx];               // exp(w) * dk
    }

    if (tid < F_DIM) {
        eb_lds[tid] = exu_b[tid];
        float v = dense_b[tid];
        #pragma unroll
        for (int off = 32; off > 0; off >>= 1) v += __shfl_down(v, off, 64);
        if (tid == 0) sdb = v;
    }

    const int row0 = blockIdx.x * ROWS_PER_BLOCK;

    for (int g = 0; g < NPASS; ++g) {
        const int b0 = row0 + g * RGROUP;

        __syncthreads();   // prev pass done; eb_lds/sdb visible (first iter)
        if (tid < RGROUP * F_DIM) {        // 512 threads stage 8 rows
            const int f = tid & (F_DIM - 1);
            const int r = tid >> 6;        // coalesced global read per r-group
            float x = X[(size_t)(b0 + r) * F_DIM + f];
            xe_lds[f][r] = x - eb_lds[f];
        }
        __syncthreads();

        float acc[RGROUP];
        #pragma unroll
        for (int rr = 0; rr < RGROUP; ++rr) acc[rr] = 0.0f;

        const float4* xe4 = (const float4*)xe_lds;  // [F_DIM][2] float4
        #pragma unroll
        for (int j = 0; j < FPT; ++j) {
            const float ewl = ewl_r[j];
            const float ewd = ewd_r[j];
            // whole wave reads same address -> LDS broadcast, conflict-free
            const float4 xa = xe4[(fbase + j) * 2 + 0];  // rows 0..3
            const float4 xb = xe4[(fbase + j) * 2 + 1];  // rows 4..7
            const float xr[RGROUP] = {xa.x, xa.y, xa.z, xa.w,
                                      xb.x, xb.y, xb.z, xb.w};
            #pragma unroll
            for (int rr = 0; rr < RGROUP; ++rr) {
                const float xe  = xr[rr];
                const float t   = __builtin_amdgcn_exp2f(xe * ewl);
                const float u   = t + 1.0f;
                const float den = __fmaf_rn(u, u, 1.0f);
                const float r   = __builtin_amdgcn_rcpf(den);
                const float q   = __fmaf_rn(-2.0f, r, 1.0f);
                acc[rr] = __fmaf_rn(xe * ewd, q, acc[rr]);
            }
        }

        // --- wave shuffle reduce, then cross-wave via LDS ---
        #pragma unroll
        for (int rr = 0; rr < RGROUP; ++rr) {
            float v = acc[rr];
            #pragma unroll
            for (int off = 32; off > 0; off >>= 1) v += __shfl_down(v, off, 64);
            acc[rr] = v;
        }
        const int wave = tid >> 6;
        const int lane = tid & 63;
        if (lane == 0) {
            #pragma unroll
            for (int rr = 0; rr < RGROUP; ++rr) red_lds[wave][rr] = acc[rr];
        }
        __syncthreads();
        if (tid < 128) {
            // wave 0 -> rows 0..3, wave 1 -> rows 4..7
            const int r = (tid & 3) + (tid >> 6) * 4;
            const int w = (tid & 63) >> 2;
            float v = red_lds[w][r];
            #pragma unroll
            for (int off = 32; off >= 4; off >>= 1) v += __shfl_down(v, off, 64);
            if ((tid & 63) < 4) out[b0 + r] = v + sdb;
        }
    }
}

extern "C" void kernel_launch(void* const* d_in, const int* in_sizes, int n_in,
                              void* d_out, int out_size, void* d_ws, size_t ws_size,
                              hipStream_t stream) {
    const float* X  = (const float*)d_in[0];
    const float* ew = (const float*)d_in[1];
    const float* eb = (const float*)d_in[2];
    const float* dk = (const float*)d_in[3];
    const float* db = (const float*)d_in[4];
    float* out = (float*)d_out;

    dim3 grid(B_ROWS / ROWS_PER_BLOCK);   // 512 blocks
    dim3 block(BLOCK);                    // 1024 threads = 16 waves
    nam_kernel<<<grid, block, 0, stream>>>(X, ew, eb, dk, db, out);
}